// Round 3
// baseline (206.881 us; speedup 1.0000x reference)
//
#include <hip/hip_runtime.h>

// Speech MSA with dynamic windows.
// B=4, T=4160 (W=64 word tokens + F=4096 frames), E=256, H=4, D=64,
// LOCAL_SIZE=15 (pad 7), chunk = F/W = 64, n = B*H = 16.
//
// R3: all three gemms (qkv, expa, out) on MFMA f32_32x32x16_f16 with fp32
// hi/lo split (3-product), NO LDS and NO barriers in the gemms — fragments
// loaded directly from L2-resident hi/lo f16 operands, register
// double-buffered over the 8 (or 2) K-iterations. One fused conversion
// kernel produces all f16 operands.

#define QN 4194304ull          // 16 * 4096 * 64 elements (head-layout buffers)
#define XN 4259840             // 4 * 4160 * 256 elements (full x)

typedef _Float16 h8 __attribute__((ext_vector_type(8)));
typedef float f32x16 __attribute__((ext_vector_type(16)));

#define MFMA3(acc, ah_, al_, bh_, bl_)                                    \
  do {                                                                    \
    acc = __builtin_amdgcn_mfma_f32_32x32x16_f16(ah_, bh_, acc, 0, 0, 0); \
    acc = __builtin_amdgcn_mfma_f32_32x32x16_f16(ah_, bl_, acc, 0, 0, 0); \
    acc = __builtin_amdgcn_mfma_f32_32x32x16_f16(al_, bh_, acc, 0, 0, 0); \
  } while (0)

// ------------------------------------------------- fused conversion kernel
// blocks [0,4160): x -> xh/xl (hi/lo f16), float4 per thread
// blocks [4160,4928): WqT   [768][256]
// blocks [4928,5184): WoT   [256][256]
// blocks [5184,5440): wmT   [b][f][w] hi/lo (LDS 64x64 tile transpose)
// blocks [5440,5444): xT    [b][c][w] hi/lo (word-token rows transposed)
__global__ __launch_bounds__(256) void conv_all(
    const float* __restrict__ x, const float* __restrict__ wm,
    const float* __restrict__ Wq, const float* __restrict__ Wo,
    _Float16* __restrict__ xh, _Float16* __restrict__ xl,
    _Float16* __restrict__ wqth, _Float16* __restrict__ wqtl,
    _Float16* __restrict__ woth, _Float16* __restrict__ wotl,
    _Float16* __restrict__ wmth, _Float16* __restrict__ wmtl,
    _Float16* __restrict__ xth, _Float16* __restrict__ xtl) {
  __shared__ float S[64 * 260];
  const int g = blockIdx.x, tid = threadIdx.x;
  if (g < 4160) {
    int i = g * 256 + tid;
    float4 v = ((const float4*)x)[i];
    _Float16 h0 = (_Float16)v.x, h1 = (_Float16)v.y;
    _Float16 h2 = (_Float16)v.z, h3 = (_Float16)v.w;
    _Float16 hh[4] = {h0, h1, h2, h3};
    _Float16 ll[4] = {(_Float16)(v.x - (float)h0), (_Float16)(v.y - (float)h1),
                      (_Float16)(v.z - (float)h2), (_Float16)(v.w - (float)h3)};
    *(float2*)(xh + 4ull * i) = *(float2*)hh;
    *(float2*)(xl + 4ull * i) = *(float2*)ll;
  } else if (g < 4928) {
    int o = (g - 4160) * 256 + tid;
    int n = o >> 8, k = o & 255;
    float v = Wq[(size_t)k * 768 + n];
    _Float16 h = (_Float16)v;
    wqth[o] = h;
    wqtl[o] = (_Float16)(v - (float)h);
  } else if (g < 5184) {
    int o = (g - 4928) * 256 + tid;
    int n = o >> 8, k = o & 255;
    float v = Wo[(size_t)k * 256 + n];
    _Float16 h = (_Float16)v;
    woth[o] = h;
    wotl[o] = (_Float16)(v - (float)h);
  } else if (g < 5440) {
    int local = g - 5184;
    int b = local >> 6, f0 = (local & 63) * 64;
    {  // load 64(w) x 64(f) tile, coalesced over f
      int w = tid >> 2, c0 = (tid & 3) * 16;
      const float* src = wm + ((size_t)(b * 64 + w)) * 4096 + f0 + c0;
#pragma unroll
      for (int cc = 0; cc < 16; cc += 4)
        *(float4*)&S[w * 65 + c0 + cc] = *(const float4*)(src + cc);
    }
    __syncthreads();
    {  // write transposed, coalesced over w
      int fl = tid >> 2, w0 = (tid & 3) * 16;
      int f = f0 + fl;
      _Float16 hh[16], ll[16];
#pragma unroll
      for (int j = 0; j < 16; ++j) {
        float v = S[(w0 + j) * 65 + fl];
        _Float16 h = (_Float16)v;
        hh[j] = h;
        ll[j] = (_Float16)(v - (float)h);
      }
      size_t o = ((size_t)b * 4096 + f) * 64 + w0;
      *(float4*)(wmth + o) = *(float4*)&hh[0];
      *(float4*)(wmth + o + 8) = *(float4*)&hh[8];
      *(float4*)(wmtl + o) = *(float4*)&ll[0];
      *(float4*)(wmtl + o + 8) = *(float4*)&ll[8];
    }
  } else {
    int b = g - 5440;
    {  // load 64(w) x 256(c), coalesced
      int w = tid >> 2, c0 = (tid & 3) * 64;
      const float* src = x + ((size_t)(b * 4160 + w)) * 256 + c0;
#pragma unroll
      for (int cc = 0; cc < 64; cc += 4)
        *(float4*)&S[w * 260 + c0 + cc] = *(const float4*)(src + cc);
    }
    __syncthreads();
    {  // thread per channel c, write [c][w] rows
      int c = tid;
      _Float16 hh[64], ll[64];
#pragma unroll
      for (int w = 0; w < 64; ++w) {
        float v = S[w * 260 + c];
        _Float16 h = (_Float16)v;
        hh[w] = h;
        ll[w] = (_Float16)(v - (float)h);
      }
      size_t o = ((size_t)b * 256 + c) * 64;
#pragma unroll
      for (int w = 0; w < 64; w += 8) {
        *(float4*)(xth + o + w) = *(float4*)&hh[w];
        *(float4*)(xtl + o + w) = *(float4*)&ll[w];
      }
    }
  }
}

// ---------------------------------------------------------------- K1: QKV gemm
// M=16384, N=768, K=256. Block 128x128, 4 waves, wave = 2m x 2n 32-tiles.
// No LDS; fragments direct from L2; register double-buffer over 8 K-iters.
__global__ __launch_bounds__(256) void qkv_mfma(
    const _Float16* __restrict__ xh, const _Float16* __restrict__ xl,
    const _Float16* __restrict__ wth, const _Float16* __restrict__ wtl,
    const float* __restrict__ bq,
    float* __restrict__ Qb, float* __restrict__ Kb, float* __restrict__ Vb) {
  const int tid = threadIdx.x;
  const int wave = tid >> 6, lane = tid & 63;
  const int ln = lane & 31, half = lane >> 5;
  const int mw = (wave & 1) * 64, nw = (wave >> 1) * 64;
  const int m0 = blockIdx.x * 128, n0 = blockIdx.y * 128;

  size_t aoff[2], boff[2];
#pragma unroll
  for (int t = 0; t < 2; ++t) {
    int row = m0 + mw + t * 32 + ln;
    aoff[t] = ((size_t)((row >> 12) * 4160 + 64 + (row & 4095))) * 256 + half * 8;
    boff[t] = (size_t)(n0 + nw + t * 32 + ln) * 256 + half * 8;
  }

  f32x16 acc[2][2] = {};
  h8 Ah[2][2][2], Al[2][2][2], Bh[2][2][2], Bl[2][2][2];  // [buf][tile][ks]

#pragma unroll
  for (int t = 0; t < 2; ++t)
#pragma unroll
    for (int s = 0; s < 2; ++s) {
      Ah[0][t][s] = *(const h8*)(xh + aoff[t] + s * 16);
      Al[0][t][s] = *(const h8*)(xl + aoff[t] + s * 16);
      Bh[0][t][s] = *(const h8*)(wth + boff[t] + s * 16);
      Bl[0][t][s] = *(const h8*)(wtl + boff[t] + s * 16);
    }

#pragma unroll
  for (int it = 0; it < 8; ++it) {
    const int cur = it & 1, nxt = cur ^ 1;
    if (it < 7) {
      const int k = (it + 1) * 32;
#pragma unroll
      for (int t = 0; t < 2; ++t)
#pragma unroll
        for (int s = 0; s < 2; ++s) {
          Ah[nxt][t][s] = *(const h8*)(xh + aoff[t] + k + s * 16);
          Al[nxt][t][s] = *(const h8*)(xl + aoff[t] + k + s * 16);
          Bh[nxt][t][s] = *(const h8*)(wth + boff[t] + k + s * 16);
          Bl[nxt][t][s] = *(const h8*)(wtl + boff[t] + k + s * 16);
        }
    }
#pragma unroll
    for (int s = 0; s < 2; ++s)
#pragma unroll
      for (int mi = 0; mi < 2; ++mi)
#pragma unroll
        for (int ni = 0; ni < 2; ++ni)
          MFMA3(acc[mi][ni], Ah[cur][mi][s], Al[cur][mi][s], Bh[cur][ni][s],
                Bl[cur][ni][s]);
  }

  // C/D: col = ln, row = (reg&3) + 8*(reg>>2) + 4*half
#pragma unroll
  for (int ni = 0; ni < 2; ++ni) {
    const int c = n0 + nw + ni * 32 + ln;
    const int which = c >> 8, e = c & 255;
    const int h = e >> 6, d = e & 63;
    float* dst = (which == 0) ? Qb : (which == 1) ? Kb : Vb;
    const float sc = (which == 0) ? 0.125f : 1.0f;
    const float bias = bq[c];
#pragma unroll
    for (int mi = 0; mi < 2; ++mi) {
      const int rb = m0 + mw + mi * 32 + 4 * half;
#pragma unroll
      for (int reg = 0; reg < 16; ++reg) {
        int rr = rb + (reg & 3) + 8 * (reg >> 2);
        int b2 = rr >> 12, f2 = rr & 4095;
        dst[(((size_t)(b2 * 4 + h)) * 4096 + f2) * 64 + d] =
            (acc[mi][ni][reg] + bias) * sc;
      }
    }
  }
}

// ---------------------------------------------------------------- K2: expa
// Per b: EX[b*4+h][f][d] = wmT[b] (4096x64) @ xT[b]^T  (K=64, N=256 channels)
__global__ __launch_bounds__(256) void expa_mfma(
    const _Float16* __restrict__ wmth, const _Float16* __restrict__ wmtl,
    const _Float16* __restrict__ xth, const _Float16* __restrict__ xtl,
    float* __restrict__ ex) {
  const int tid = threadIdx.x;
  const int wave = tid >> 6, lane = tid & 63;
  const int ln = lane & 31, half = lane >> 5;
  const int mw = (wave & 1) * 32, nw = (wave >> 1) * 32;
  const int m0 = blockIdx.x * 64, n0 = blockIdx.y * 64;
  const int b = blockIdx.z;

  const size_t aoff = ((size_t)(b * 4096 + m0 + mw + ln)) * 64 + half * 8;
  const size_t boff = ((size_t)(b * 256 + n0 + nw + ln)) * 64 + half * 8;

  f32x16 acc = {};
#pragma unroll
  for (int k0 = 0; k0 < 64; k0 += 32)
#pragma unroll
    for (int s = 0; s < 2; ++s) {
      h8 ah = *(const h8*)(wmth + aoff + k0 + s * 16);
      h8 al = *(const h8*)(wmtl + aoff + k0 + s * 16);
      h8 bh = *(const h8*)(xth + boff + k0 + s * 16);
      h8 bl = *(const h8*)(xtl + boff + k0 + s * 16);
      MFMA3(acc, ah, al, bh, bl);
    }

  const int c = n0 + nw + ln;
  const int h = c >> 6, d = c & 63;
  const int n = b * 4 + h;
  const int rb = m0 + mw + 4 * half;
#pragma unroll
  for (int reg = 0; reg < 16; ++reg) {
    int f = rb + (reg & 3) + 8 * (reg >> 2);
    ex[((size_t)n * 4096 + f) * 64 + d] = acc[reg];
  }
}

// ---------------------------------------------------------------- K3: attention
__global__ __launch_bounds__(256) void attn_kernel(
    const float* __restrict__ Qb, const float* __restrict__ Kb,
    const float* __restrict__ Vb, const float* __restrict__ ex,
    _Float16* __restrict__ OFh, _Float16* __restrict__ OFl) {
  __shared__ float Ks[78][68];
  __shared__ float Vs[78][68];
  __shared__ float s0s[64];
  __shared__ float red[2];
  const int tid = threadIdx.x;
  const int w = blockIdx.x;
  const int n = blockIdx.y;
  const int f0 = w * 64;

  for (int idx = tid; idx < 78 * 16; idx += 256) {
    int rr = idx >> 4, c = (idx & 15) * 4;
    int g = f0 - 7 + rr;
    float4 kv = {0.f, 0.f, 0.f, 0.f}, vv = {0.f, 0.f, 0.f, 0.f};
    if (g >= 0 && g < 4096) {
      size_t base = ((size_t)n * 4096 + g) * 64 + c;
      kv = *(const float4*)(Kb + base);
      vv = *(const float4*)(Vb + base);
    }
    *(float4*)&Ks[rr][c] = kv;
    *(float4*)&Vs[rr][c] = vv;
  }
  __syncthreads();

  const int i = tid >> 2, q = tid & 3;
  const int f = f0 + i;
  const size_t qbase = ((size_t)n * 4096 + f) * 64 + q * 16;
  float4 q0 = *(const float4*)(Qb + qbase);
  float4 q1 = *(const float4*)(Qb + qbase + 4);
  float4 q2 = *(const float4*)(Qb + qbase + 8);
  float4 q3 = *(const float4*)(Qb + qbase + 12);
  float4 e0 = *(const float4*)(ex + qbase);
  float4 e1 = *(const float4*)(ex + qbase + 4);
  float4 e2 = *(const float4*)(ex + qbase + 8);
  float4 e3 = *(const float4*)(ex + qbase + 12);

  float s0 = q0.x * e0.x + q0.y * e0.y + q0.z * e0.z + q0.w * e0.w +
             q1.x * e1.x + q1.y * e1.y + q1.z * e1.z + q1.w * e1.w +
             q2.x * e2.x + q2.y * e2.y + q2.z * e2.z + q2.w * e2.w +
             q3.x * e3.x + q3.y * e3.y + q3.z * e3.z + q3.w * e3.w;
  s0 += __shfl_xor(s0, 1);
  s0 += __shfl_xor(s0, 2);

  float sj[15];
#pragma unroll
  for (int j = 0; j < 15; ++j) {
    const float* kr = &Ks[i + j][q * 16];
    float4 k0 = *(const float4*)(kr);
    float4 k1 = *(const float4*)(kr + 4);
    float4 k2 = *(const float4*)(kr + 8);
    float4 k3 = *(const float4*)(kr + 12);
    float s = q0.x * k0.x + q0.y * k0.y + q0.z * k0.z + q0.w * k0.w +
              q1.x * k1.x + q1.y * k1.y + q1.z * k1.z + q1.w * k1.w +
              q2.x * k2.x + q2.y * k2.y + q2.z * k2.z + q2.w * k2.w +
              q3.x * k3.x + q3.y * k3.y + q3.z * k3.z + q3.w * k3.w;
    s += __shfl_xor(s, 1);
    s += __shfl_xor(s, 2);
    sj[j] = s;
  }

  if (q == 0) s0s[i] = s0;
  __syncthreads();
  if (tid < 64) {
    float v = s0s[tid];
    float m = v;
    for (int o = 1; o < 64; o <<= 1) m = fmaxf(m, __shfl_xor(m, o));
    float ee = expf(v - m);
    float s = ee;
    for (int o = 1; o < 64; o <<= 1) s += __shfl_xor(s, o);
    if (tid == 0) { red[0] = m; red[1] = s; }
  }
  __syncthreads();
  const float wt = expf(s0 - red[0]) / red[1];

  float mx = sj[0];
#pragma unroll
  for (int j = 1; j < 15; ++j) mx = fmaxf(mx, sj[j]);
  float pj[15], den = 0.f;
#pragma unroll
  for (int j = 0; j < 15; ++j) { pj[j] = expf(sj[j] - mx); den += pj[j]; }
  const float inv = 1.0f / den;

  float o[16] = {wt * e0.x, wt * e0.y, wt * e0.z, wt * e0.w,
                 wt * e1.x, wt * e1.y, wt * e1.z, wt * e1.w,
                 wt * e2.x, wt * e2.y, wt * e2.z, wt * e2.w,
                 wt * e3.x, wt * e3.y, wt * e3.z, wt * e3.w};
#pragma unroll
  for (int j = 0; j < 15; ++j) {
    float wj = pj[j] * inv;
    const float* vr = &Vs[i + j][q * 16];
#pragma unroll
    for (int dd = 0; dd < 16; ++dd) o[dd] = fmaf(wj, vr[dd], o[dd]);
  }
  _Float16 oh[16], ol[16];
#pragma unroll
  for (int dd = 0; dd < 16; ++dd) {
    _Float16 hh = (_Float16)o[dd];
    oh[dd] = hh;
    ol[dd] = (_Float16)(o[dd] - (float)hh);
  }
  *(float4*)(OFh + qbase) = *(float4*)&oh[0];
  *(float4*)(OFh + qbase + 8) = *(float4*)&oh[8];
  *(float4*)(OFl + qbase) = *(float4*)&ol[0];
  *(float4*)(OFl + qbase + 8) = *(float4*)&ol[8];
}

// ---------------------------------------------------------------- K4: out proj
// M=16640, N=256, K=256. Block 64x64, 4 waves, wave = 1m x 1n. No LDS.
__global__ __launch_bounds__(256) void out_mfma(
    const _Float16* __restrict__ xh, const _Float16* __restrict__ xl,
    const _Float16* __restrict__ ofh, const _Float16* __restrict__ ofl,
    const _Float16* __restrict__ wth, const _Float16* __restrict__ wtl,
    const float* __restrict__ bo, float* __restrict__ out) {
  const int tid = threadIdx.x;
  const int wave = tid >> 6, lane = tid & 63;
  const int ln = lane & 31, half = lane >> 5;
  const int mw = (wave & 1) * 32, nw = (wave >> 1) * 32;
  const int m0 = blockIdx.x * 64, n0 = blockIdx.y * 64;

  const int m = m0 + mw + ln;
  const int b = m / 4160, t = m % 4160;
  const bool useX = (t < 64);
  const size_t xbase = ((size_t)(b * 4160 + t)) * 256 + half * 8;
  const size_t obase = ((size_t)(b * 4) * 4096 + (t - 64)) * 64 + half * 8;
  const size_t boff = (size_t)(n0 + nw + ln) * 256 + half * 8;

  f32x16 acc = {};
  h8 Ah[2][2], Al[2][2], Bh[2][2], Bl[2][2];

#define OUT_LOAD(buf, k0_)                                                   \
  do {                                                                       \
    _Pragma("unroll") for (int s = 0; s < 2; ++s) {                          \
      const int kk = (k0_) + s * 16;                                         \
      size_t ao = useX ? (xbase + kk)                                        \
                       : (obase + (size_t)((kk + half * 8) >> 6) * 262144 +  \
                          (((kk + half * 8) & 63) - half * 8));              \
      Ah[buf][s] = *(const h8*)((useX ? xh : ofh) + ao);                     \
      Al[buf][s] = *(const h8*)((useX ? xl : ofl) + ao);                     \
      Bh[buf][s] = *(const h8*)(wth + boff + kk);                            \
      Bl[buf][s] = *(const h8*)(wtl + boff + kk);                            \
    }                                                                        \
  } while (0)

  OUT_LOAD(0, 0);
#pragma unroll
  for (int it = 0; it < 8; ++it) {
    const int cur = it & 1, nxt = cur ^ 1;
    if (it < 7) OUT_LOAD(nxt, (it + 1) * 32);
#pragma unroll
    for (int s = 0; s < 2; ++s)
      MFMA3(acc, Ah[cur][s], Al[cur][s], Bh[cur][s], Bl[cur][s]);
  }
#undef OUT_LOAD

  const int c = n0 + nw + ln;
  const float bias = bo[c];
  const int rb = m0 + mw + 4 * half;
#pragma unroll
  for (int reg = 0; reg < 16; ++reg) {
    int rr = rb + (reg & 3) + 8 * (reg >> 2);
    out[(size_t)rr * 256 + c] = acc[reg] + bias;
  }
}

// ---------------------------------------------------------------- launch
extern "C" void kernel_launch(void* const* d_in, const int* in_sizes, int n_in,
                              void* d_out, int out_size, void* d_ws, size_t ws_size,
                              hipStream_t stream) {
  const float* x  = (const float*)d_in[0];
  const float* wm = (const float*)d_in[1];
  const float* Wq = (const float*)d_in[2];
  const float* bq = (const float*)d_in[3];
  const float* Wo = (const float*)d_in[4];
  const float* bo = (const float*)d_in[5];
  float* out = (float*)d_out;

  float* Qb = (float*)d_ws;
  float* Kb = Qb + QN;
  float* Vb = Kb + QN;
  float* EX = Vb + QN;
  _Float16* xh   = (_Float16*)(EX + QN);
  _Float16* xl   = xh + XN;
  _Float16* OFh  = xl + XN;
  _Float16* OFl  = OFh + QN;
  _Float16* Wqth = OFl + QN;        // [768][256]
  _Float16* Wqtl = Wqth + 196608;
  _Float16* Woth = Wqtl + 196608;   // [256][256]
  _Float16* Wotl = Woth + 65536;
  _Float16* wmTh = Wotl + 65536;    // [4][4096][64]
  _Float16* wmTl = wmTh + 1048576;
  _Float16* xTh  = wmTl + 1048576;  // [4][256][64]
  _Float16* xTl  = xTh + 65536;
  // total ~106 MB of workspace

  conv_all<<<dim3(5444), 256, 0, stream>>>(x, wm, Wq, Wo, xh, xl, Wqth, Wqtl,
                                           Woth, Wotl, wmTh, wmTl, xTh, xTl);
  qkv_mfma<<<dim3(128, 6), 256, 0, stream>>>(xh, xl, Wqth, Wqtl, bq, Qb, Kb, Vb);
  expa_mfma<<<dim3(64, 4, 4), 256, 0, stream>>>(wmTh, wmTl, xTh, xTl, EX);
  attn_kernel<<<dim3(64, 16), 256, 0, stream>>>(Qb, Kb, Vb, EX, OFh, OFl);
  out_mfma<<<dim3(260, 4), 256, 0, stream>>>(xh, xl, OFh, OFl, Woth, Wotl, bo, out);
}

// Round 4
// 156.524 us; speedup vs baseline: 1.3217x; 1.3217x over previous
//
#include <hip/hip_runtime.h>

// Speech MSA with dynamic windows.
// B=4, T=4160 (W=64 word tokens + F=4096 frames), E=256, H=4, D=64,
// LOCAL_SIZE=15 (pad 7), chunk = F/W = 64, n = B*H = 16.
//
// R4: gemms back to LDS staging (R3's direct-from-L2 fragment gathers were
// latency-bound: 64 cache lines per load instr). 128x128 qkv tile, 64x64
// out/expa tiles, software-pipelined: next iter's global loads issued before
// the MFMA block. LDS rows padded for 16B alignment + <=4-way banking.
// Numerics identical to R3 (f16 hi/lo 3-product, fp32 intermediates).

#define QN 4194304ull          // 16 * 4096 * 64 elements (head-layout buffers)
#define XN 4259840             // 4 * 4160 * 256 elements (full x)

typedef _Float16 h8 __attribute__((ext_vector_type(8)));
typedef float f32x16 __attribute__((ext_vector_type(16)));

#define MFMA3(acc, ah_, al_, bh_, bl_)                                    \
  do {                                                                    \
    acc = __builtin_amdgcn_mfma_f32_32x32x16_f16(ah_, bh_, acc, 0, 0, 0); \
    acc = __builtin_amdgcn_mfma_f32_32x32x16_f16(ah_, bl_, acc, 0, 0, 0); \
    acc = __builtin_amdgcn_mfma_f32_32x32x16_f16(al_, bh_, acc, 0, 0, 0); \
  } while (0)

// ------------------------------------------------- fused conversion kernel
__global__ __launch_bounds__(256) void conv_all(
    const float* __restrict__ x, const float* __restrict__ wm,
    const float* __restrict__ Wq, const float* __restrict__ Wo,
    _Float16* __restrict__ xh, _Float16* __restrict__ xl,
    _Float16* __restrict__ wqth, _Float16* __restrict__ wqtl,
    _Float16* __restrict__ woth, _Float16* __restrict__ wotl,
    _Float16* __restrict__ wmth, _Float16* __restrict__ wmtl,
    _Float16* __restrict__ xth, _Float16* __restrict__ xtl) {
  __shared__ float S[64 * 260];
  const int g = blockIdx.x, tid = threadIdx.x;
  if (g < 4160) {
    int i = g * 256 + tid;
    float4 v = ((const float4*)x)[i];
    _Float16 h0 = (_Float16)v.x, h1 = (_Float16)v.y;
    _Float16 h2 = (_Float16)v.z, h3 = (_Float16)v.w;
    _Float16 hh[4] = {h0, h1, h2, h3};
    _Float16 ll[4] = {(_Float16)(v.x - (float)h0), (_Float16)(v.y - (float)h1),
                      (_Float16)(v.z - (float)h2), (_Float16)(v.w - (float)h3)};
    *(float2*)(xh + 4ull * i) = *(float2*)hh;
    *(float2*)(xl + 4ull * i) = *(float2*)ll;
  } else if (g < 4928) {
    int o = (g - 4160) * 256 + tid;
    int n = o >> 8, k = o & 255;
    float v = Wq[(size_t)k * 768 + n];
    _Float16 h = (_Float16)v;
    wqth[o] = h;
    wqtl[o] = (_Float16)(v - (float)h);
  } else if (g < 5184) {
    int o = (g - 4928) * 256 + tid;
    int n = o >> 8, k = o & 255;
    float v = Wo[(size_t)k * 256 + n];
    _Float16 h = (_Float16)v;
    woth[o] = h;
    wotl[o] = (_Float16)(v - (float)h);
  } else if (g < 5440) {
    int local = g - 5184;
    int b = local >> 6, f0 = (local & 63) * 64;
    {
      int w = tid >> 2, c0 = (tid & 3) * 16;
      const float* src = wm + ((size_t)(b * 64 + w)) * 4096 + f0 + c0;
#pragma unroll
      for (int cc = 0; cc < 16; cc += 4)
        *(float4*)&S[w * 65 + c0 + cc] = *(const float4*)(src + cc);
    }
    __syncthreads();
    {
      int fl = tid >> 2, w0 = (tid & 3) * 16;
      int f = f0 + fl;
      _Float16 hh[16], ll[16];
#pragma unroll
      for (int j = 0; j < 16; ++j) {
        float v = S[(w0 + j) * 65 + fl];
        _Float16 h = (_Float16)v;
        hh[j] = h;
        ll[j] = (_Float16)(v - (float)h);
      }
      size_t o = ((size_t)b * 4096 + f) * 64 + w0;
      *(float4*)(wmth + o) = *(float4*)&hh[0];
      *(float4*)(wmth + o + 8) = *(float4*)&hh[8];
      *(float4*)(wmtl + o) = *(float4*)&ll[0];
      *(float4*)(wmtl + o + 8) = *(float4*)&ll[8];
    }
  } else {
    int b = g - 5440;
    {
      int w = tid >> 2, c0 = (tid & 3) * 64;
      const float* src = x + ((size_t)(b * 4160 + w)) * 256 + c0;
#pragma unroll
      for (int cc = 0; cc < 64; cc += 4)
        *(float4*)&S[w * 260 + c0 + cc] = *(const float4*)(src + cc);
    }
    __syncthreads();
    {
      int c = tid;
      _Float16 hh[64], ll[64];
#pragma unroll
      for (int w = 0; w < 64; ++w) {
        float v = S[w * 260 + c];
        _Float16 h = (_Float16)v;
        hh[w] = h;
        ll[w] = (_Float16)(v - (float)h);
      }
      size_t o = ((size_t)b * 256 + c) * 64;
#pragma unroll
      for (int w = 0; w < 64; w += 8) {
        *(float4*)(xth + o + w) = *(float4*)&hh[w];
        *(float4*)(xtl + o + w) = *(float4*)&ll[w];
      }
    }
  }
}

// ---------------------------------------------------------------- K1: QKV gemm
// M=16384, N=768, K=256. Block 128x128, 4 waves (each 64x64), BK=32 x 8 iters.
// LDS rows padded to 40 f16 (80B: 16B-aligned frags, 4-way banking max).
__global__ __launch_bounds__(256) void qkv_mfma(
    const _Float16* __restrict__ xh, const _Float16* __restrict__ xl,
    const _Float16* __restrict__ wth, const _Float16* __restrict__ wtl,
    const float* __restrict__ bq,
    float* __restrict__ Qb, float* __restrict__ Kb, float* __restrict__ Vb) {
  __shared__ _Float16 Ah[128][40], Al[128][40], Bh[128][40], Bl[128][40];
  const int tid = threadIdx.x;
  const int wave = tid >> 6, lane = tid & 63;
  const int ln = lane & 31, half = lane >> 5;
  const int mw = (wave & 1) * 64, nw = (wave >> 1) * 64;
  const int m0 = blockIdx.x * 128, n0 = blockIdx.y * 128;

  const int sr = tid >> 1;            // staging row 0..127
  const int sc = (tid & 1) * 16;      // f16 col offset {0,16}
  const int am = m0 + sr;
  const size_t arow =
      ((size_t)((am >> 12) * 4160 + 64 + (am & 4095))) * 256 + sc;
  const size_t brow = (size_t)(n0 + sr) * 256 + sc;

  float4 rah0, rah1, ral0, ral1, rbh0, rbh1, rbl0, rbl1;
#define QLOAD(k0_)                                       \
  do {                                                   \
    rah0 = *(const float4*)(xh + arow + (k0_));          \
    rah1 = *(const float4*)(xh + arow + (k0_) + 8);      \
    ral0 = *(const float4*)(xl + arow + (k0_));          \
    ral1 = *(const float4*)(xl + arow + (k0_) + 8);      \
    rbh0 = *(const float4*)(wth + brow + (k0_));         \
    rbh1 = *(const float4*)(wth + brow + (k0_) + 8);     \
    rbl0 = *(const float4*)(wtl + brow + (k0_));         \
    rbl1 = *(const float4*)(wtl + brow + (k0_) + 8);     \
  } while (0)

  QLOAD(0);
  f32x16 acc[2][2] = {};

  for (int it = 0; it < 8; ++it) {
    __syncthreads();
    *(float4*)&Ah[sr][sc] = rah0;
    *(float4*)&Ah[sr][sc + 8] = rah1;
    *(float4*)&Al[sr][sc] = ral0;
    *(float4*)&Al[sr][sc + 8] = ral1;
    *(float4*)&Bh[sr][sc] = rbh0;
    *(float4*)&Bh[sr][sc + 8] = rbh1;
    *(float4*)&Bl[sr][sc] = rbl0;
    *(float4*)&Bl[sr][sc + 8] = rbl1;
    __syncthreads();
    if (it < 7) QLOAD((it + 1) * 32);   // overlap next loads with MFMAs
#pragma unroll
    for (int ks = 0; ks < 2; ++ks) {
      const int kc = ks * 16 + half * 8;
      h8 a0h = *(const h8*)&Ah[mw + ln][kc];
      h8 a0l = *(const h8*)&Al[mw + ln][kc];
      h8 a1h = *(const h8*)&Ah[mw + 32 + ln][kc];
      h8 a1l = *(const h8*)&Al[mw + 32 + ln][kc];
      h8 b0h = *(const h8*)&Bh[nw + ln][kc];
      h8 b0l = *(const h8*)&Bl[nw + ln][kc];
      h8 b1h = *(const h8*)&Bh[nw + 32 + ln][kc];
      h8 b1l = *(const h8*)&Bl[nw + 32 + ln][kc];
      MFMA3(acc[0][0], a0h, a0l, b0h, b0l);
      MFMA3(acc[0][1], a0h, a0l, b1h, b1l);
      MFMA3(acc[1][0], a1h, a1l, b0h, b0l);
      MFMA3(acc[1][1], a1h, a1l, b1h, b1l);
    }
  }
#undef QLOAD

  // C/D: col = ln, row = (reg&3) + 8*(reg>>2) + 4*half
#pragma unroll
  for (int ni = 0; ni < 2; ++ni) {
    const int c = n0 + nw + ni * 32 + ln;
    const int which = c >> 8, e = c & 255;
    const int h = e >> 6, d = e & 63;
    float* dst = (which == 0) ? Qb : (which == 1) ? Kb : Vb;
    const float sc2 = (which == 0) ? 0.125f : 1.0f;
    const float bias = bq[c];
#pragma unroll
    for (int mi = 0; mi < 2; ++mi) {
      const int rb = m0 + mw + mi * 32 + 4 * half;
#pragma unroll
      for (int reg = 0; reg < 16; ++reg) {
        int rr = rb + (reg & 3) + 8 * (reg >> 2);
        int b2 = rr >> 12, f2 = rr & 4095;
        dst[(((size_t)(b2 * 4 + h)) * 4096 + f2) * 64 + d] =
            (acc[mi][ni][reg] + bias) * sc2;
      }
    }
  }
}

// ---------------------------------------------------------------- K2: expa
// Per b: EX[b*4+h][f][d] = wmT[b] (4096x64) @ xT[b]^T. Block 64x64, K=64.
__global__ __launch_bounds__(256) void expa_mfma(
    const _Float16* __restrict__ wmth, const _Float16* __restrict__ wmtl,
    const _Float16* __restrict__ xth, const _Float16* __restrict__ xtl,
    float* __restrict__ ex) {
  __shared__ _Float16 Ah[64][72], Al[64][72], Bh[64][72], Bl[64][72];
  const int tid = threadIdx.x;
  const int wave = tid >> 6, lane = tid & 63;
  const int ln = lane & 31, half = lane >> 5;
  const int mw = (wave & 1) * 32, nw = (wave >> 1) * 32;
  const int m0 = blockIdx.x * 64, n0 = blockIdx.y * 64;
  const int b = blockIdx.z;

  const int sr = tid >> 2, sc = (tid & 3) * 16;
  const size_t aoff = ((size_t)(b * 4096 + m0 + sr)) * 64 + sc;
  const size_t boff = ((size_t)(b * 256 + n0 + sr)) * 64 + sc;

  *(float4*)&Ah[sr][sc] = *(const float4*)(wmth + aoff);
  *(float4*)&Ah[sr][sc + 8] = *(const float4*)(wmth + aoff + 8);
  *(float4*)&Al[sr][sc] = *(const float4*)(wmtl + aoff);
  *(float4*)&Al[sr][sc + 8] = *(const float4*)(wmtl + aoff + 8);
  *(float4*)&Bh[sr][sc] = *(const float4*)(xth + boff);
  *(float4*)&Bh[sr][sc + 8] = *(const float4*)(xth + boff + 8);
  *(float4*)&Bl[sr][sc] = *(const float4*)(xtl + boff);
  *(float4*)&Bl[sr][sc + 8] = *(const float4*)(xtl + boff + 8);
  __syncthreads();

  f32x16 acc = {};
#pragma unroll
  for (int ks = 0; ks < 4; ++ks) {
    const int kc = ks * 16 + half * 8;
    h8 ah = *(const h8*)&Ah[mw + ln][kc];
    h8 al = *(const h8*)&Al[mw + ln][kc];
    h8 bh = *(const h8*)&Bh[nw + ln][kc];
    h8 bl = *(const h8*)&Bl[nw + ln][kc];
    MFMA3(acc, ah, al, bh, bl);
  }

  const int c = n0 + nw + ln;
  const int h = c >> 6, d = c & 63;
  const int n = b * 4 + h;
  const int rb = m0 + mw + 4 * half;
#pragma unroll
  for (int reg = 0; reg < 16; ++reg) {
    int f = rb + (reg & 3) + 8 * (reg >> 2);
    ex[((size_t)n * 4096 + f) * 64 + d] = acc[reg];
  }
}

// ---------------------------------------------------------------- K3: attention
__global__ __launch_bounds__(256) void attn_kernel(
    const float* __restrict__ Qb, const float* __restrict__ Kb,
    const float* __restrict__ Vb, const float* __restrict__ ex,
    _Float16* __restrict__ OFh, _Float16* __restrict__ OFl) {
  __shared__ float Ks[78][68];
  __shared__ float Vs[78][68];
  __shared__ float s0s[64];
  __shared__ float red[2];
  const int tid = threadIdx.x;
  const int w = blockIdx.x;
  const int n = blockIdx.y;
  const int f0 = w * 64;

  for (int idx = tid; idx < 78 * 16; idx += 256) {
    int rr = idx >> 4, c = (idx & 15) * 4;
    int g = f0 - 7 + rr;
    float4 kv = {0.f, 0.f, 0.f, 0.f}, vv = {0.f, 0.f, 0.f, 0.f};
    if (g >= 0 && g < 4096) {
      size_t base = ((size_t)n * 4096 + g) * 64 + c;
      kv = *(const float4*)(Kb + base);
      vv = *(const float4*)(Vb + base);
    }
    *(float4*)&Ks[rr][c] = kv;
    *(float4*)&Vs[rr][c] = vv;
  }
  __syncthreads();

  const int i = tid >> 2, q = tid & 3;
  const int f = f0 + i;
  const size_t qbase = ((size_t)n * 4096 + f) * 64 + q * 16;
  float4 q0 = *(const float4*)(Qb + qbase);
  float4 q1 = *(const float4*)(Qb + qbase + 4);
  float4 q2 = *(const float4*)(Qb + qbase + 8);
  float4 q3 = *(const float4*)(Qb + qbase + 12);
  float4 e0 = *(const float4*)(ex + qbase);
  float4 e1 = *(const float4*)(ex + qbase + 4);
  float4 e2 = *(const float4*)(ex + qbase + 8);
  float4 e3 = *(const float4*)(ex + qbase + 12);

  float s0 = q0.x * e0.x + q0.y * e0.y + q0.z * e0.z + q0.w * e0.w +
             q1.x * e1.x + q1.y * e1.y + q1.z * e1.z + q1.w * e1.w +
             q2.x * e2.x + q2.y * e2.y + q2.z * e2.z + q2.w * e2.w +
             q3.x * e3.x + q3.y * e3.y + q3.z * e3.z + q3.w * e3.w;
  s0 += __shfl_xor(s0, 1);
  s0 += __shfl_xor(s0, 2);

  float sj[15];
#pragma unroll
  for (int j = 0; j < 15; ++j) {
    const float* kr = &Ks[i + j][q * 16];
    float4 k0 = *(const float4*)(kr);
    float4 k1 = *(const float4*)(kr + 4);
    float4 k2 = *(const float4*)(kr + 8);
    float4 k3 = *(const float4*)(kr + 12);
    float s = q0.x * k0.x + q0.y * k0.y + q0.z * k0.z + q0.w * k0.w +
              q1.x * k1.x + q1.y * k1.y + q1.z * k1.z + q1.w * k1.w +
              q2.x * k2.x + q2.y * k2.y + q2.z * k2.z + q2.w * k2.w +
              q3.x * k3.x + q3.y * k3.y + q3.z * k3.z + q3.w * k3.w;
    s += __shfl_xor(s, 1);
    s += __shfl_xor(s, 2);
    sj[j] = s;
  }

  if (q == 0) s0s[i] = s0;
  __syncthreads();
  if (tid < 64) {
    float v = s0s[tid];
    float m = v;
    for (int o = 1; o < 64; o <<= 1) m = fmaxf(m, __shfl_xor(m, o));
    float ee = expf(v - m);
    float s = ee;
    for (int o = 1; o < 64; o <<= 1) s += __shfl_xor(s, o);
    if (tid == 0) { red[0] = m; red[1] = s; }
  }
  __syncthreads();
  const float wt = expf(s0 - red[0]) / red[1];

  float mx = sj[0];
#pragma unroll
  for (int j = 1; j < 15; ++j) mx = fmaxf(mx, sj[j]);
  float pj[15], den = 0.f;
#pragma unroll
  for (int j = 0; j < 15; ++j) { pj[j] = expf(sj[j] - mx); den += pj[j]; }
  const float inv = 1.0f / den;

  float o[16] = {wt * e0.x, wt * e0.y, wt * e0.z, wt * e0.w,
                 wt * e1.x, wt * e1.y, wt * e1.z, wt * e1.w,
                 wt * e2.x, wt * e2.y, wt * e2.z, wt * e2.w,
                 wt * e3.x, wt * e3.y, wt * e3.z, wt * e3.w};
#pragma unroll
  for (int j = 0; j < 15; ++j) {
    float wj = pj[j] * inv;
    const float* vr = &Vs[i + j][q * 16];
#pragma unroll
    for (int dd = 0; dd < 16; ++dd) o[dd] = fmaf(wj, vr[dd], o[dd]);
  }
  _Float16 oh[16], ol[16];
#pragma unroll
  for (int dd = 0; dd < 16; ++dd) {
    _Float16 hh = (_Float16)o[dd];
    oh[dd] = hh;
    ol[dd] = (_Float16)(o[dd] - (float)hh);
  }
  *(float4*)(OFh + qbase) = *(float4*)&oh[0];
  *(float4*)(OFh + qbase + 8) = *(float4*)&oh[8];
  *(float4*)(OFl + qbase) = *(float4*)&ol[0];
  *(float4*)(OFl + qbase + 8) = *(float4*)&ol[8];
}

// ---------------------------------------------------------------- K4: out proj
// M=16640, N=256, K=256. Block 64x64, 4 waves (each 32x32), BK=64 x 4 iters.
__global__ __launch_bounds__(256) void out_mfma(
    const _Float16* __restrict__ xh, const _Float16* __restrict__ xl,
    const _Float16* __restrict__ ofh, const _Float16* __restrict__ ofl,
    const _Float16* __restrict__ wth, const _Float16* __restrict__ wtl,
    const float* __restrict__ bo, float* __restrict__ out) {
  __shared__ _Float16 Ah[64][72], Al[64][72], Bh[64][72], Bl[64][72];
  const int tid = threadIdx.x;
  const int wave = tid >> 6, lane = tid & 63;
  const int ln = lane & 31, half = lane >> 5;
  const int mw = (wave & 1) * 32, nw = (wave >> 1) * 32;
  const int m0 = blockIdx.x * 64, n0 = blockIdx.y * 64;

  const int sr = tid >> 2, sc = (tid & 3) * 16;
  const int m = m0 + sr;
  const int b = m / 4160, tt = m % 4160;
  const bool useX = (tt < 64);
  const size_t xbase = ((size_t)(b * 4160 + tt)) * 256 + sc;
  const long obase = ((long)(b * 4) * 4096 + (tt - 64)) * 64 + sc;
  const size_t bbase = (size_t)(n0 + sr) * 256 + sc;

  float4 ra0, ra1, rl0, rl1, rb0, rb1, rc0, rc1;
#define OLOAD(k0_)                                                       \
  do {                                                                   \
    const _Float16* ph;                                                  \
    const _Float16* pl;                                                  \
    size_t o_;                                                           \
    if (useX) {                                                          \
      ph = xh; pl = xl; o_ = xbase + (k0_);                              \
    } else {                                                             \
      ph = ofh; pl = ofl;                                                \
      o_ = (size_t)(obase + (long)((k0_) >> 6) * 262144);                \
    }                                                                    \
    ra0 = *(const float4*)(ph + o_);                                     \
    ra1 = *(const float4*)(ph + o_ + 8);                                 \
    rl0 = *(const float4*)(pl + o_);                                     \
    rl1 = *(const float4*)(pl + o_ + 8);                                 \
    rb0 = *(const float4*)(wth + bbase + (k0_));                         \
    rb1 = *(const float4*)(wth + bbase + (k0_) + 8);                     \
    rc0 = *(const float4*)(wtl + bbase + (k0_));                         \
    rc1 = *(const float4*)(wtl + bbase + (k0_) + 8);                     \
  } while (0)

  OLOAD(0);
  f32x16 acc = {};

  for (int it = 0; it < 4; ++it) {
    __syncthreads();
    *(float4*)&Ah[sr][sc] = ra0;
    *(float4*)&Ah[sr][sc + 8] = ra1;
    *(float4*)&Al[sr][sc] = rl0;
    *(float4*)&Al[sr][sc + 8] = rl1;
    *(float4*)&Bh[sr][sc] = rb0;
    *(float4*)&Bh[sr][sc + 8] = rb1;
    *(float4*)&Bl[sr][sc] = rc0;
    *(float4*)&Bl[sr][sc + 8] = rc1;
    __syncthreads();
    if (it < 3) OLOAD((it + 1) * 64);
#pragma unroll
    for (int ks = 0; ks < 4; ++ks) {
      const int kc = ks * 16 + half * 8;
      h8 ah = *(const h8*)&Ah[mw + ln][kc];
      h8 al = *(const h8*)&Al[mw + ln][kc];
      h8 bh = *(const h8*)&Bh[nw + ln][kc];
      h8 bl = *(const h8*)&Bl[nw + ln][kc];
      MFMA3(acc, ah, al, bh, bl);
    }
  }
#undef OLOAD

  const int c = n0 + nw + ln;
  const float bias = bo[c];
  const int rb = m0 + mw + 4 * half;
#pragma unroll
  for (int reg = 0; reg < 16; ++reg) {
    int rr = rb + (reg & 3) + 8 * (reg >> 2);
    out[(size_t)rr * 256 + c] = acc[reg] + bias;
  }
}

// ---------------------------------------------------------------- launch
extern "C" void kernel_launch(void* const* d_in, const int* in_sizes, int n_in,
                              void* d_out, int out_size, void* d_ws, size_t ws_size,
                              hipStream_t stream) {
  const float* x  = (const float*)d_in[0];
  const float* wm = (const float*)d_in[1];
  const float* Wq = (const float*)d_in[2];
  const float* bq = (const float*)d_in[3];
  const float* Wo = (const float*)d_in[4];
  const float* bo = (const float*)d_in[5];
  float* out = (float*)d_out;

  float* Qb = (float*)d_ws;
  float* Kb = Qb + QN;
  float* Vb = Kb + QN;
  float* EX = Vb + QN;
  _Float16* xh   = (_Float16*)(EX + QN);
  _Float16* xl   = xh + XN;
  _Float16* OFh  = xl + XN;
  _Float16* OFl  = OFh + QN;
  _Float16* Wqth = OFl + QN;        // [768][256]
  _Float16* Wqtl = Wqth + 196608;
  _Float16* Woth = Wqtl + 196608;   // [256][256]
  _Float16* Wotl = Woth + 65536;
  _Float16* wmTh = Wotl + 65536;    // [4][4096][64]
  _Float16* wmTl = wmTh + 1048576;
  _Float16* xTh  = wmTl + 1048576;  // [4][256][64]
  _Float16* xTl  = xTh + 65536;

  conv_all<<<dim3(5444), 256, 0, stream>>>(x, wm, Wq, Wo, xh, xl, Wqth, Wqtl,
                                           Woth, Wotl, wmTh, wmTl, xTh, xTl);
  qkv_mfma<<<dim3(128, 6), 256, 0, stream>>>(xh, xl, Wqth, Wqtl, bq, Qb, Kb, Vb);
  expa_mfma<<<dim3(64, 4, 4), 256, 0, stream>>>(wmTh, wmTl, xTh, xTl, EX);
  attn_kernel<<<dim3(64, 16), 256, 0, stream>>>(Qb, Kb, Vb, EX, OFh, OFl);
  out_mfma<<<dim3(260, 4), 256, 0, stream>>>(xh, xl, OFh, OFl, Woth, Wotl, bo, out);
}

// Round 5
// 150.755 us; speedup vs baseline: 1.3723x; 1.0383x over previous
//
#include <hip/hip_runtime.h>

// Speech MSA with dynamic windows.
// B=4, T=4160 (W=64 word tokens + F=4096 frames), E=256, H=4, D=64,
// LOCAL_SIZE=15 (pad 7), chunk = F/W = 64, n = B*H = 16.
//
// R5: (a) qkv stages fp32 x directly, hi/lo f16 split done in registers
// (removes the 60 MB conv pass over x); (b) expa fused into attn (each attn
// block computes its own 64x64 expa tile via MFMA into LDS — removes the EX
// global round-trip and one dispatch); (c) out-proj reads a tiny pre-split
// xw buffer for the 256 word-token rows. Numerics bit-identical to R4.

#define QN 4194304ull          // 16 * 4096 * 64 elements (head-layout buffers)

typedef _Float16 h8 __attribute__((ext_vector_type(8)));
typedef float f32x16 __attribute__((ext_vector_type(16)));

#define MFMA3(acc, ah_, al_, bh_, bl_)                                    \
  do {                                                                    \
    acc = __builtin_amdgcn_mfma_f32_32x32x16_f16(ah_, bh_, acc, 0, 0, 0); \
    acc = __builtin_amdgcn_mfma_f32_32x32x16_f16(ah_, bl_, acc, 0, 0, 0); \
    acc = __builtin_amdgcn_mfma_f32_32x32x16_f16(al_, bh_, acc, 0, 0, 0); \
  } while (0)

// ------------------------------------------------- small conversion kernel
// g [0,768):      WqT  [768][256] hi/lo
// g [768,1024):   WoT  [256][256] hi/lo
// g [1024,1280):  wmT  [b][f][w]  hi/lo (LDS 64x64 tile transpose)
// g [1280,1284):  xT   [b][c][w]  hi/lo (word-token rows transposed)
// g [1284,1348):  xw   [b][t<64][c] hi/lo (word-token rows, row-major)
__global__ __launch_bounds__(256) void conv_small(
    const float* __restrict__ x, const float* __restrict__ wm,
    const float* __restrict__ Wq, const float* __restrict__ Wo,
    _Float16* __restrict__ wqth, _Float16* __restrict__ wqtl,
    _Float16* __restrict__ woth, _Float16* __restrict__ wotl,
    _Float16* __restrict__ wmth, _Float16* __restrict__ wmtl,
    _Float16* __restrict__ xth, _Float16* __restrict__ xtl,
    _Float16* __restrict__ xwh, _Float16* __restrict__ xwl) {
  __shared__ float S[64 * 260];
  const int g = blockIdx.x, tid = threadIdx.x;
  if (g < 768) {
    int o = g * 256 + tid;
    int n = o >> 8, k = o & 255;
    float v = Wq[(size_t)k * 768 + n];
    _Float16 h = (_Float16)v;
    wqth[o] = h;
    wqtl[o] = (_Float16)(v - (float)h);
  } else if (g < 1024) {
    int o = (g - 768) * 256 + tid;
    int n = o >> 8, k = o & 255;
    float v = Wo[(size_t)k * 256 + n];
    _Float16 h = (_Float16)v;
    woth[o] = h;
    wotl[o] = (_Float16)(v - (float)h);
  } else if (g < 1280) {
    int local = g - 1024;
    int b = local >> 6, f0 = (local & 63) * 64;
    {
      int w = tid >> 2, c0 = (tid & 3) * 16;
      const float* src = wm + ((size_t)(b * 64 + w)) * 4096 + f0 + c0;
#pragma unroll
      for (int cc = 0; cc < 16; cc += 4)
        *(float4*)&S[w * 65 + c0 + cc] = *(const float4*)(src + cc);
    }
    __syncthreads();
    {
      int fl = tid >> 2, w0 = (tid & 3) * 16;
      int f = f0 + fl;
      _Float16 hh[16], ll[16];
#pragma unroll
      for (int j = 0; j < 16; ++j) {
        float v = S[(w0 + j) * 65 + fl];
        _Float16 h = (_Float16)v;
        hh[j] = h;
        ll[j] = (_Float16)(v - (float)h);
      }
      size_t o = ((size_t)b * 4096 + f) * 64 + w0;
      *(float4*)(wmth + o) = *(float4*)&hh[0];
      *(float4*)(wmth + o + 8) = *(float4*)&hh[8];
      *(float4*)(wmtl + o) = *(float4*)&ll[0];
      *(float4*)(wmtl + o + 8) = *(float4*)&ll[8];
    }
  } else if (g < 1284) {
    int b = g - 1280;
    {
      int w = tid >> 2, c0 = (tid & 3) * 64;
      const float* src = x + ((size_t)(b * 4160 + w)) * 256 + c0;
#pragma unroll
      for (int cc = 0; cc < 64; cc += 4)
        *(float4*)&S[w * 260 + c0 + cc] = *(const float4*)(src + cc);
    }
    __syncthreads();
    {
      int c = tid;
      _Float16 hh[64], ll[64];
#pragma unroll
      for (int w = 0; w < 64; ++w) {
        float v = S[w * 260 + c];
        _Float16 h = (_Float16)v;
        hh[w] = h;
        ll[w] = (_Float16)(v - (float)h);
      }
      size_t o = ((size_t)b * 256 + c) * 64;
#pragma unroll
      for (int w = 0; w < 64; w += 8) {
        *(float4*)(xth + o + w) = *(float4*)&hh[w];
        *(float4*)(xtl + o + w) = *(float4*)&ll[w];
      }
    }
  } else {
    int i = (g - 1284) * 256 + tid;        // float4 index, 0..16383
    int b = i >> 12, rem = i & 4095;
    int r = rem >> 6, c4 = rem & 63;
    float4 v = *(const float4*)(x + ((size_t)(b * 4160 + r)) * 256 + c4 * 4);
    _Float16 h0 = (_Float16)v.x, h1 = (_Float16)v.y;
    _Float16 h2 = (_Float16)v.z, h3 = (_Float16)v.w;
    _Float16 hh[4] = {h0, h1, h2, h3};
    _Float16 ll[4] = {(_Float16)(v.x - (float)h0), (_Float16)(v.y - (float)h1),
                      (_Float16)(v.z - (float)h2), (_Float16)(v.w - (float)h3)};
    *(float2*)(xwh + 4ull * i) = *(float2*)hh;
    *(float2*)(xwl + 4ull * i) = *(float2*)ll;
  }
}

// ---------------------------------------------------------------- K1: QKV gemm
// M=16384, N=768, K=256. Block 128x128, 4 waves (each 64x64), BK=32 x 8 iters.
// A staged from fp32 x with in-register hi/lo split (overlaps MFMA phase).
__global__ __launch_bounds__(256) void qkv_mfma(
    const float* __restrict__ x,
    const _Float16* __restrict__ wth, const _Float16* __restrict__ wtl,
    const float* __restrict__ bq,
    float* __restrict__ Qb, float* __restrict__ Kb, float* __restrict__ Vb) {
  __shared__ _Float16 Ah[128][40], Al[128][40], Bh[128][40], Bl[128][40];
  const int tid = threadIdx.x;
  const int wave = tid >> 6, lane = tid & 63;
  const int ln = lane & 31, half = lane >> 5;
  const int mw = (wave & 1) * 64, nw = (wave >> 1) * 64;
  const int m0 = blockIdx.x * 128, n0 = blockIdx.y * 128;

  const int sr = tid >> 1;            // staging row 0..127
  const int sc = (tid & 1) * 16;      // col offset {0,16}
  const int am = m0 + sr;
  const size_t arow =
      ((size_t)((am >> 12) * 4160 + 64 + (am & 4095))) * 256 + sc;
  const size_t brow = (size_t)(n0 + sr) * 256 + sc;

  float4 rah0, rah1, ral0, ral1, rbh0, rbh1, rbl0, rbl1;
#define QLOAD(k0_)                                                     \
  do {                                                                 \
    float4 fx0 = *(const float4*)(x + arow + (k0_));                   \
    float4 fx1 = *(const float4*)(x + arow + (k0_) + 4);               \
    float4 fx2 = *(const float4*)(x + arow + (k0_) + 8);               \
    float4 fx3 = *(const float4*)(x + arow + (k0_) + 12);              \
    rbh0 = *(const float4*)(wth + brow + (k0_));                       \
    rbh1 = *(const float4*)(wth + brow + (k0_) + 8);                   \
    rbl0 = *(const float4*)(wtl + brow + (k0_));                       \
    rbl1 = *(const float4*)(wtl + brow + (k0_) + 8);                   \
    float fs[16] = {fx0.x, fx0.y, fx0.z, fx0.w, fx1.x, fx1.y, fx1.z,   \
                    fx1.w, fx2.x, fx2.y, fx2.z, fx2.w, fx3.x, fx3.y,   \
                    fx3.z, fx3.w};                                     \
    _Float16 hh[16], ll[16];                                           \
    _Pragma("unroll") for (int j = 0; j < 16; ++j) {                   \
      _Float16 h_ = (_Float16)fs[j];                                   \
      hh[j] = h_;                                                      \
      ll[j] = (_Float16)(fs[j] - (float)h_);                           \
    }                                                                  \
    rah0 = *(float4*)&hh[0];                                           \
    rah1 = *(float4*)&hh[8];                                           \
    ral0 = *(float4*)&ll[0];                                           \
    ral1 = *(float4*)&ll[8];                                           \
  } while (0)

  QLOAD(0);
  f32x16 acc[2][2] = {};

  for (int it = 0; it < 8; ++it) {
    __syncthreads();
    *(float4*)&Ah[sr][sc] = rah0;
    *(float4*)&Ah[sr][sc + 8] = rah1;
    *(float4*)&Al[sr][sc] = ral0;
    *(float4*)&Al[sr][sc + 8] = ral1;
    *(float4*)&Bh[sr][sc] = rbh0;
    *(float4*)&Bh[sr][sc + 8] = rbh1;
    *(float4*)&Bl[sr][sc] = rbl0;
    *(float4*)&Bl[sr][sc + 8] = rbl1;
    __syncthreads();
    if (it < 7) QLOAD((it + 1) * 32);   // loads + converts overlap MFMAs
#pragma unroll
    for (int ks = 0; ks < 2; ++ks) {
      const int kc = ks * 16 + half * 8;
      h8 a0h = *(const h8*)&Ah[mw + ln][kc];
      h8 a0l = *(const h8*)&Al[mw + ln][kc];
      h8 a1h = *(const h8*)&Ah[mw + 32 + ln][kc];
      h8 a1l = *(const h8*)&Al[mw + 32 + ln][kc];
      h8 b0h = *(const h8*)&Bh[nw + ln][kc];
      h8 b0l = *(const h8*)&Bl[nw + ln][kc];
      h8 b1h = *(const h8*)&Bh[nw + 32 + ln][kc];
      h8 b1l = *(const h8*)&Bl[nw + 32 + ln][kc];
      MFMA3(acc[0][0], a0h, a0l, b0h, b0l);
      MFMA3(acc[0][1], a0h, a0l, b1h, b1l);
      MFMA3(acc[1][0], a1h, a1l, b0h, b0l);
      MFMA3(acc[1][1], a1h, a1l, b1h, b1l);
    }
  }
#undef QLOAD

  // C/D: col = ln, row = (reg&3) + 8*(reg>>2) + 4*half
#pragma unroll
  for (int ni = 0; ni < 2; ++ni) {
    const int c = n0 + nw + ni * 32 + ln;
    const int which = c >> 8, e = c & 255;
    const int h = e >> 6, d = e & 63;
    float* dst = (which == 0) ? Qb : (which == 1) ? Kb : Vb;
    const float sc2 = (which == 0) ? 0.125f : 1.0f;
    const float bias = bq[c];
#pragma unroll
    for (int mi = 0; mi < 2; ++mi) {
      const int rb = m0 + mw + mi * 32 + 4 * half;
#pragma unroll
      for (int reg = 0; reg < 16; ++reg) {
        int rr = rb + (reg & 3) + 8 * (reg >> 2);
        int b2 = rr >> 12, f2 = rr & 4095;
        dst[(((size_t)(b2 * 4 + h)) * 4096 + f2) * 64 + d] =
            (acc[mi][ni][reg] + bias) * sc2;
      }
    }
  }
}

// ------------------------------------------------- K2: fused expa + attention
// one block per (n, window): phase 1 computes the 64x64 expa tile via MFMA
// (wave = one 32x32 tile) into LDS; phase 2 = local attention.
__global__ __launch_bounds__(256) void attn_fused(
    const float* __restrict__ Qb, const float* __restrict__ Kb,
    const float* __restrict__ Vb,
    const _Float16* __restrict__ wmth, const _Float16* __restrict__ wmtl,
    const _Float16* __restrict__ xth, const _Float16* __restrict__ xtl,
    _Float16* __restrict__ OFh, _Float16* __restrict__ OFl) {
  __shared__ float Ks[78][68];
  __shared__ float Vs[78][68];
  __shared__ float EXs[64][68];
  __shared__ float s0s[64];
  __shared__ float red[2];
  const int tid = threadIdx.x;
  const int w = blockIdx.x;
  const int n = blockIdx.y;
  const int f0 = w * 64;
  const int b = n >> 2, h = n & 3;

  // ---- stage K/V rows f0-7 .. f0+70 (zero-padded)
  for (int idx = tid; idx < 78 * 16; idx += 256) {
    int rr = idx >> 4, c = (idx & 15) * 4;
    int g = f0 - 7 + rr;
    float4 kv = {0.f, 0.f, 0.f, 0.f}, vv = {0.f, 0.f, 0.f, 0.f};
    if (g >= 0 && g < 4096) {
      size_t base = ((size_t)n * 4096 + g) * 64 + c;
      kv = *(const float4*)(Kb + base);
      vv = *(const float4*)(Vb + base);
    }
    *(float4*)&Ks[rr][c] = kv;
    *(float4*)&Vs[rr][c] = vv;
  }

  // ---- phase 1: expa tile (64 frames x 64 channels of head h), K=64 over w
  {
    const int wave = tid >> 6, lane = tid & 63;
    const int ln = lane & 31, half = lane >> 5;
    const int mi = wave & 1, ni = wave >> 1;
    const size_t arow = ((size_t)(b * 4096 + f0 + mi * 32 + ln)) * 64 + half * 8;
    const size_t brow = ((size_t)(b * 256 + h * 64 + ni * 32 + ln)) * 64 + half * 8;
    f32x16 eacc = {};
#pragma unroll
    for (int ks = 0; ks < 4; ++ks) {
      const int kc = ks * 16;
      h8 ah = *(const h8*)(wmth + arow + kc);
      h8 al = *(const h8*)(wmtl + arow + kc);
      h8 bh = *(const h8*)(xth + brow + kc);
      h8 bl = *(const h8*)(xtl + brow + kc);
      MFMA3(eacc, ah, al, bh, bl);
    }
    const int col = ni * 32 + ln;
    const int rb = mi * 32 + 4 * half;
#pragma unroll
    for (int reg = 0; reg < 16; ++reg)
      EXs[rb + (reg & 3) + 8 * (reg >> 2)][col] = eacc[reg];
  }
  __syncthreads();

  // ---- phase 2: attention
  const int i = tid >> 2, q = tid & 3;
  const int f = f0 + i;
  const size_t qbase = ((size_t)n * 4096 + f) * 64 + q * 16;
  float4 q0 = *(const float4*)(Qb + qbase);
  float4 q1 = *(const float4*)(Qb + qbase + 4);
  float4 q2 = *(const float4*)(Qb + qbase + 8);
  float4 q3 = *(const float4*)(Qb + qbase + 12);
  float4 e0 = *(const float4*)&EXs[i][q * 16];
  float4 e1 = *(const float4*)&EXs[i][q * 16 + 4];
  float4 e2 = *(const float4*)&EXs[i][q * 16 + 8];
  float4 e3 = *(const float4*)&EXs[i][q * 16 + 12];

  float s0 = q0.x * e0.x + q0.y * e0.y + q0.z * e0.z + q0.w * e0.w +
             q1.x * e1.x + q1.y * e1.y + q1.z * e1.z + q1.w * e1.w +
             q2.x * e2.x + q2.y * e2.y + q2.z * e2.z + q2.w * e2.w +
             q3.x * e3.x + q3.y * e3.y + q3.z * e3.z + q3.w * e3.w;
  s0 += __shfl_xor(s0, 1);
  s0 += __shfl_xor(s0, 2);

  float sj[15];
#pragma unroll
  for (int j = 0; j < 15; ++j) {
    const float* kr = &Ks[i + j][q * 16];
    float4 k0 = *(const float4*)(kr);
    float4 k1 = *(const float4*)(kr + 4);
    float4 k2 = *(const float4*)(kr + 8);
    float4 k3 = *(const float4*)(kr + 12);
    float s = q0.x * k0.x + q0.y * k0.y + q0.z * k0.z + q0.w * k0.w +
              q1.x * k1.x + q1.y * k1.y + q1.z * k1.z + q1.w * k1.w +
              q2.x * k2.x + q2.y * k2.y + q2.z * k2.z + q2.w * k2.w +
              q3.x * k3.x + q3.y * k3.y + q3.z * k3.z + q3.w * k3.w;
    s += __shfl_xor(s, 1);
    s += __shfl_xor(s, 2);
    sj[j] = s;
  }

  if (q == 0) s0s[i] = s0;
  __syncthreads();
  if (tid < 64) {
    float v = s0s[tid];
    float m = v;
    for (int o = 1; o < 64; o <<= 1) m = fmaxf(m, __shfl_xor(m, o));
    float ee = expf(v - m);
    float s = ee;
    for (int o = 1; o < 64; o <<= 1) s += __shfl_xor(s, o);
    if (tid == 0) { red[0] = m; red[1] = s; }
  }
  __syncthreads();
  const float wt = expf(s0 - red[0]) / red[1];

  float mx = sj[0];
#pragma unroll
  for (int j = 1; j < 15; ++j) mx = fmaxf(mx, sj[j]);
  float pj[15], den = 0.f;
#pragma unroll
  for (int j = 0; j < 15; ++j) { pj[j] = expf(sj[j] - mx); den += pj[j]; }
  const float inv = 1.0f / den;

  float o[16] = {wt * e0.x, wt * e0.y, wt * e0.z, wt * e0.w,
                 wt * e1.x, wt * e1.y, wt * e1.z, wt * e1.w,
                 wt * e2.x, wt * e2.y, wt * e2.z, wt * e2.w,
                 wt * e3.x, wt * e3.y, wt * e3.z, wt * e3.w};
#pragma unroll
  for (int j = 0; j < 15; ++j) {
    float wj = pj[j] * inv;
    const float* vr = &Vs[i + j][q * 16];
#pragma unroll
    for (int dd = 0; dd < 16; ++dd) o[dd] = fmaf(wj, vr[dd], o[dd]);
  }
  _Float16 oh[16], ol[16];
#pragma unroll
  for (int dd = 0; dd < 16; ++dd) {
    _Float16 hh = (_Float16)o[dd];
    oh[dd] = hh;
    ol[dd] = (_Float16)(o[dd] - (float)hh);
  }
  *(float4*)(OFh + qbase) = *(float4*)&oh[0];
  *(float4*)(OFh + qbase + 8) = *(float4*)&oh[8];
  *(float4*)(OFl + qbase) = *(float4*)&ol[0];
  *(float4*)(OFl + qbase + 8) = *(float4*)&ol[8];
}

// ---------------------------------------------------------------- K3: out proj
// M=16640, N=256, K=256. Block 64x64, 4 waves (each 32x32), BK=64 x 4 iters.
__global__ __launch_bounds__(256) void out_mfma(
    const _Float16* __restrict__ xwh, const _Float16* __restrict__ xwl,
    const _Float16* __restrict__ ofh, const _Float16* __restrict__ ofl,
    const _Float16* __restrict__ wth, const _Float16* __restrict__ wtl,
    const float* __restrict__ bo, float* __restrict__ out) {
  __shared__ _Float16 Ah[64][72], Al[64][72], Bh[64][72], Bl[64][72];
  const int tid = threadIdx.x;
  const int wave = tid >> 6, lane = tid & 63;
  const int ln = lane & 31, half = lane >> 5;
  const int mw = (wave & 1) * 32, nw = (wave >> 1) * 32;
  const int m0 = blockIdx.x * 64, n0 = blockIdx.y * 64;

  const int sr = tid >> 2, sc = (tid & 2) * 8;   // two threads per 32-f16 row half? no:
  // staging: 256 threads stage 64 rows x 64 k: sr=tid>>2 row, (tid&3)*16 col
  const int sc4 = (tid & 3) * 16;
  const int m = m0 + sr;
  const int b = m / 4160, tt = m % 4160;
  const bool useX = (tt < 64);
  const size_t xbase = ((size_t)(b * 64 + tt)) * 256 + sc4;
  const long obase = ((long)(b * 4) * 4096 + (tt - 64)) * 64 + sc4;
  const size_t bbase = (size_t)(n0 + sr) * 256 + sc4;

  float4 ra0, ra1, rl0, rl1, rb0, rb1, rc0, rc1;
#define OLOAD(k0_)                                                       \
  do {                                                                   \
    const _Float16* ph;                                                  \
    const _Float16* pl;                                                  \
    size_t o_;                                                           \
    if (useX) {                                                          \
      ph = xwh; pl = xwl; o_ = xbase + (k0_);                            \
    } else {                                                             \
      ph = ofh; pl = ofl;                                                \
      o_ = (size_t)(obase + (long)((k0_) >> 6) * 262144);                \
    }                                                                    \
    ra0 = *(const float4*)(ph + o_);                                     \
    ra1 = *(const float4*)(ph + o_ + 8);                                 \
    rl0 = *(const float4*)(pl + o_);                                     \
    rl1 = *(const float4*)(pl + o_ + 8);                                 \
    rb0 = *(const float4*)(wth + bbase + (k0_));                         \
    rb1 = *(const float4*)(wth + bbase + (k0_) + 8);                     \
    rc0 = *(const float4*)(wtl + bbase + (k0_));                         \
    rc1 = *(const float4*)(wtl + bbase + (k0_) + 8);                     \
  } while (0)

  OLOAD(0);
  f32x16 acc = {};

  for (int it = 0; it < 4; ++it) {
    __syncthreads();
    *(float4*)&Ah[sr][sc4] = ra0;
    *(float4*)&Ah[sr][sc4 + 8] = ra1;
    *(float4*)&Al[sr][sc4] = rl0;
    *(float4*)&Al[sr][sc4 + 8] = rl1;
    *(float4*)&Bh[sr][sc4] = rb0;
    *(float4*)&Bh[sr][sc4 + 8] = rb1;
    *(float4*)&Bl[sr][sc4] = rc0;
    *(float4*)&Bl[sr][sc4 + 8] = rc1;
    __syncthreads();
    if (it < 3) OLOAD((it + 1) * 64);
#pragma unroll
    for (int ks = 0; ks < 4; ++ks) {
      const int kc = ks * 16 + half * 8;
      h8 ah = *(const h8*)&Ah[mw + ln][kc];
      h8 al = *(const h8*)&Al[mw + ln][kc];
      h8 bh = *(const h8*)&Bh[nw + ln][kc];
      h8 bl = *(const h8*)&Bl[nw + ln][kc];
      MFMA3(acc, ah, al, bh, bl);
    }
  }
#undef OLOAD

  const int c = n0 + nw + ln;
  const float bias = bo[c];
  const int rb = m0 + mw + 4 * half;
#pragma unroll
  for (int reg = 0; reg < 16; ++reg) {
    int rr = rb + (reg & 3) + 8 * (reg >> 2);
    out[(size_t)rr * 256 + c] = acc[reg] + bias;
  }
  (void)sc;
}

// ---------------------------------------------------------------- launch
extern "C" void kernel_launch(void* const* d_in, const int* in_sizes, int n_in,
                              void* d_out, int out_size, void* d_ws, size_t ws_size,
                              hipStream_t stream) {
  const float* x  = (const float*)d_in[0];
  const float* wm = (const float*)d_in[1];
  const float* Wq = (const float*)d_in[2];
  const float* bq = (const float*)d_in[3];
  const float* Wo = (const float*)d_in[4];
  const float* bo = (const float*)d_in[5];
  float* out = (float*)d_out;

  float* Qb = (float*)d_ws;
  float* Kb = Qb + QN;
  float* Vb = Kb + QN;
  _Float16* OFh  = (_Float16*)(Vb + QN);
  _Float16* OFl  = OFh + QN;
  _Float16* Wqth = OFl + QN;        // [768][256]
  _Float16* Wqtl = Wqth + 196608;
  _Float16* Woth = Wqtl + 196608;   // [256][256]
  _Float16* Wotl = Woth + 65536;
  _Float16* wmTh = Wotl + 65536;    // [4][4096][64]
  _Float16* wmTl = wmTh + 1048576;
  _Float16* xTh  = wmTl + 1048576;  // [4][256][64]
  _Float16* xTl  = xTh + 65536;
  _Float16* xwh  = xTl + 65536;     // [4][64][256]
  _Float16* xwl  = xwh + 65536;
  // total ~73 MB of workspace

  conv_small<<<dim3(1348), 256, 0, stream>>>(x, wm, Wq, Wo, Wqth, Wqtl, Woth,
                                             Wotl, wmTh, wmTl, xTh, xTl, xwh,
                                             xwl);
  qkv_mfma<<<dim3(128, 6), 256, 0, stream>>>(x, Wqth, Wqtl, bq, Qb, Kb, Vb);
  attn_fused<<<dim3(64, 16), 256, 0, stream>>>(Qb, Kb, Vb, wmTh, wmTl, xTh,
                                               xTl, OFh, OFl);
  out_mfma<<<dim3(260, 4), 256, 0, stream>>>(xwh, xwl, OFh, OFl, Woth, Wotl,
                                             bo, out);
}

// Round 10
// 127.435 us; speedup vs baseline: 1.6234x; 1.1830x over previous
//
#include <hip/hip_runtime.h>

// Speech MSA with dynamic windows.
// B=4, T=4160 (W=64 word tokens + F=4096 frames), E=256, H=4, D=64,
// LOCAL_SIZE=15 (pad 7), chunk = F/W = 64, n = B*H = 16.
//
// R10: R5's verified 4-kernel structure, single-product f16 MFMA (hi only —
// no Markidis lo terms). Threshold is 2.656e-2, R5's 3-product sat at 3.9e-3;
// f16 single-product error model predicts ~5e-3..1.5e-2. MFMA count /3,
// LDS+conv traffic /2. fp32 Q/K/V/scores/softmax kept. Mega-kernel/grid-
// barrier abandoned after R6-R9 (deterministic cross-block failures).

#define QN 4194304ull  // 16 * 4096 * 64 elements (head-layout buffers)

typedef _Float16 h8 __attribute__((ext_vector_type(8)));
typedef float f32x16 __attribute__((ext_vector_type(16)));

// ------------------------------------------------- small conversion kernel
// g [0,768):     WqT [768][256] f16
// g [768,1024):  WoT [256][256] f16
// g [1024,1280): wmT [b][f][w]  f16 (LDS 64x64 tile transpose)
// g [1280,1284): xT  [b][c][w]  f16 (word-token rows transposed)
__global__ __launch_bounds__(256) void conv_small(
    const float* __restrict__ x, const float* __restrict__ wm,
    const float* __restrict__ Wq, const float* __restrict__ Wo,
    _Float16* __restrict__ wqth, _Float16* __restrict__ woth,
    _Float16* __restrict__ wmth, _Float16* __restrict__ xth) {
  __shared__ float S[64 * 65];
  const int g = blockIdx.x, tid = threadIdx.x;
  if (g < 768) {
    int o = g * 256 + tid;
    int n = o >> 8, k = o & 255;
    wqth[o] = (_Float16)Wq[(size_t)k * 768 + n];
  } else if (g < 1024) {
    int o = (g - 768) * 256 + tid;
    int n = o >> 8, k = o & 255;
    woth[o] = (_Float16)Wo[(size_t)k * 256 + n];
  } else if (g < 1280) {
    int local = g - 1024;
    int b = local >> 6, f0 = (local & 63) * 64;
    {
      int w = tid >> 2, c0 = (tid & 3) * 16;
      const float* src = wm + ((size_t)(b * 64 + w)) * 4096 + f0 + c0;
#pragma unroll
      for (int cc = 0; cc < 16; cc += 4)
        *(float4*)&S[w * 65 + c0 + cc] = *(const float4*)(src + cc);
    }
    __syncthreads();
    {
      int fl = tid >> 2, w0 = (tid & 3) * 16;
      int f = f0 + fl;
      _Float16 hh[16];
#pragma unroll
      for (int j = 0; j < 16; ++j) hh[j] = (_Float16)S[(w0 + j) * 65 + fl];
      size_t o = ((size_t)b * 4096 + f) * 64 + w0;
      *(float4*)(wmth + o) = *(float4*)&hh[0];
      *(float4*)(wmth + o + 8) = *(float4*)&hh[8];
    }
  } else {
    // xT: per b, 64 word tokens x 256 channels -> [c][w]; 4 col-chunks of 64
    int local = g - 1280;   // 0..3 = b
    int b = local;
    for (int c0 = 0; c0 < 256; c0 += 64) {
      __syncthreads();
      {
        int w = tid >> 2, cl0 = (tid & 3) * 16;
        const float* src = x + ((size_t)(b * 4160 + w)) * 256 + c0 + cl0;
#pragma unroll
        for (int cc = 0; cc < 16; cc += 4)
          *(float4*)&S[w * 65 + cl0 + cc] = *(const float4*)(src + cc);
      }
      __syncthreads();
      {
        int cl = tid >> 2, w0 = (tid & 3) * 16;
        _Float16 hh[16];
#pragma unroll
        for (int j = 0; j < 16; ++j) hh[j] = (_Float16)S[(w0 + j) * 65 + cl];
        size_t o = ((size_t)(b * 256 + c0 + cl)) * 64 + w0;
        *(float4*)(xth + o) = *(float4*)&hh[0];
        *(float4*)(xth + o + 8) = *(float4*)&hh[8];
      }
    }
  }
}

// ---------------------------------------------------------------- K1: QKV gemm
// M=16384, N=768, K=256. Block 128x128, 4 waves (each 64x64), BK=32 x 8 iters.
// A staged from fp32 x with in-register f16 cvt; B from pre-converted WqT f16.
__global__ __launch_bounds__(256) void qkv_mfma(
    const float* __restrict__ x, const _Float16* __restrict__ wth,
    const float* __restrict__ bq,
    float* __restrict__ Qb, float* __restrict__ Kb, float* __restrict__ Vb) {
  __shared__ _Float16 Ah[128][40], Bh[128][40];
  const int tid = threadIdx.x;
  const int wave = tid >> 6, lane = tid & 63;
  const int ln = lane & 31, half = lane >> 5;
  const int mw = (wave & 1) * 64, nw = (wave >> 1) * 64;
  const int m0 = blockIdx.x * 128, n0 = blockIdx.y * 128;

  const int sr = tid >> 1, scq = (tid & 1) * 16;
  const int am = m0 + sr;
  const size_t arow =
      ((size_t)((am >> 12) * 4160 + 64 + (am & 4095))) * 256 + scq;
  const size_t brow = (size_t)(n0 + sr) * 256 + scq;

  float4 rah0, rah1, rbh0, rbh1;
  auto QLOAD = [&](int k0_) {
    float4 fx0 = *(const float4*)(x + arow + k0_);
    float4 fx1 = *(const float4*)(x + arow + k0_ + 4);
    float4 fx2 = *(const float4*)(x + arow + k0_ + 8);
    float4 fx3 = *(const float4*)(x + arow + k0_ + 12);
    rbh0 = *(const float4*)(wth + brow + k0_);
    rbh1 = *(const float4*)(wth + brow + k0_ + 8);
    _Float16 hh[16] = {
        (_Float16)fx0.x, (_Float16)fx0.y, (_Float16)fx0.z, (_Float16)fx0.w,
        (_Float16)fx1.x, (_Float16)fx1.y, (_Float16)fx1.z, (_Float16)fx1.w,
        (_Float16)fx2.x, (_Float16)fx2.y, (_Float16)fx2.z, (_Float16)fx2.w,
        (_Float16)fx3.x, (_Float16)fx3.y, (_Float16)fx3.z, (_Float16)fx3.w};
    rah0 = *(float4*)&hh[0];
    rah1 = *(float4*)&hh[8];
  };

  QLOAD(0);
  f32x16 acc[2][2] = {};

  for (int it = 0; it < 8; ++it) {
    __syncthreads();
    *(float4*)&Ah[sr][scq] = rah0;
    *(float4*)&Ah[sr][scq + 8] = rah1;
    *(float4*)&Bh[sr][scq] = rbh0;
    *(float4*)&Bh[sr][scq + 8] = rbh1;
    __syncthreads();
    if (it < 7) QLOAD((it + 1) * 32);
#pragma unroll
    for (int ks = 0; ks < 2; ++ks) {
      const int kc = ks * 16 + half * 8;
      h8 a0 = *(const h8*)&Ah[mw + ln][kc];
      h8 a1 = *(const h8*)&Ah[mw + 32 + ln][kc];
      h8 b0 = *(const h8*)&Bh[nw + ln][kc];
      h8 b1 = *(const h8*)&Bh[nw + 32 + ln][kc];
      acc[0][0] = __builtin_amdgcn_mfma_f32_32x32x16_f16(a0, b0, acc[0][0], 0, 0, 0);
      acc[0][1] = __builtin_amdgcn_mfma_f32_32x32x16_f16(a0, b1, acc[0][1], 0, 0, 0);
      acc[1][0] = __builtin_amdgcn_mfma_f32_32x32x16_f16(a1, b0, acc[1][0], 0, 0, 0);
      acc[1][1] = __builtin_amdgcn_mfma_f32_32x32x16_f16(a1, b1, acc[1][1], 0, 0, 0);
    }
  }

  // C/D: col = ln, row = (reg&3) + 8*(reg>>2) + 4*half
#pragma unroll
  for (int ni = 0; ni < 2; ++ni) {
    const int c = n0 + nw + ni * 32 + ln;
    const int which = c >> 8, e = c & 255;
    const int h = e >> 6, d = e & 63;
    float* dst = (which == 0) ? Qb : (which == 1) ? Kb : Vb;
    const float sc2 = (which == 0) ? 0.125f : 1.0f;
    const float bias = bq[c];
#pragma unroll
    for (int mi = 0; mi < 2; ++mi) {
      const int rb = m0 + mw + mi * 32 + 4 * half;
#pragma unroll
      for (int reg = 0; reg < 16; ++reg) {
        int rr = rb + (reg & 3) + 8 * (reg >> 2);
        int b2 = rr >> 12, f2 = rr & 4095;
        dst[(((size_t)(b2 * 4 + h)) * 4096 + f2) * 64 + d] =
            (acc[mi][ni][reg] + bias) * sc2;
      }
    }
  }
}

// ------------------------------------------------- K2: fused expa + attention
__global__ __launch_bounds__(256) void attn_fused(
    const float* __restrict__ Qb, const float* __restrict__ Kb,
    const float* __restrict__ Vb,
    const _Float16* __restrict__ wmth, const _Float16* __restrict__ xth,
    _Float16* __restrict__ OFh) {
  __shared__ float Ks[78][68];
  __shared__ float Vs[78][68];
  __shared__ float EXs[64][68];
  __shared__ float s0s[64];
  __shared__ float red[2];
  const int tid = threadIdx.x;
  const int w = blockIdx.x;
  const int n = blockIdx.y;
  const int f0 = w * 64;
  const int b = n >> 2, h = n & 3;

  for (int idx = tid; idx < 78 * 16; idx += 256) {
    int rr = idx >> 4, c = (idx & 15) * 4;
    int g = f0 - 7 + rr;
    float4 kv = {0.f, 0.f, 0.f, 0.f}, vv = {0.f, 0.f, 0.f, 0.f};
    if (g >= 0 && g < 4096) {
      size_t base = ((size_t)n * 4096 + g) * 64 + c;
      kv = *(const float4*)(Kb + base);
      vv = *(const float4*)(Vb + base);
    }
    *(float4*)&Ks[rr][c] = kv;
    *(float4*)&Vs[rr][c] = vv;
  }
  {
    const int wave = tid >> 6, lane = tid & 63;
    const int ln = lane & 31, half = lane >> 5;
    const int mi = wave & 1, ni = wave >> 1;
    const size_t arow = ((size_t)(b * 4096 + f0 + mi * 32 + ln)) * 64 + half * 8;
    const size_t brow =
        ((size_t)(b * 256 + h * 64 + ni * 32 + ln)) * 64 + half * 8;
    f32x16 eacc = {};
#pragma unroll
    for (int ks = 0; ks < 4; ++ks) {
      const int kc = ks * 16;
      h8 ah = *(const h8*)(wmth + arow + kc);
      h8 bh = *(const h8*)(xth + brow + kc);
      eacc = __builtin_amdgcn_mfma_f32_32x32x16_f16(ah, bh, eacc, 0, 0, 0);
    }
    const int col = ni * 32 + ln;
    const int rb2 = mi * 32 + 4 * half;
#pragma unroll
    for (int reg = 0; reg < 16; ++reg)
      EXs[rb2 + (reg & 3) + 8 * (reg >> 2)][col] = eacc[reg];
  }
  __syncthreads();

  const int i = tid >> 2, q = tid & 3;
  const int f = f0 + i;
  const size_t qbase = ((size_t)n * 4096 + f) * 64 + q * 16;
  float4 q0 = *(const float4*)(Qb + qbase);
  float4 q1 = *(const float4*)(Qb + qbase + 4);
  float4 q2 = *(const float4*)(Qb + qbase + 8);
  float4 q3 = *(const float4*)(Qb + qbase + 12);
  float4 e0 = *(const float4*)&EXs[i][q * 16];
  float4 e1 = *(const float4*)&EXs[i][q * 16 + 4];
  float4 e2 = *(const float4*)&EXs[i][q * 16 + 8];
  float4 e3 = *(const float4*)&EXs[i][q * 16 + 12];

  float s0 = q0.x * e0.x + q0.y * e0.y + q0.z * e0.z + q0.w * e0.w +
             q1.x * e1.x + q1.y * e1.y + q1.z * e1.z + q1.w * e1.w +
             q2.x * e2.x + q2.y * e2.y + q2.z * e2.z + q2.w * e2.w +
             q3.x * e3.x + q3.y * e3.y + q3.z * e3.z + q3.w * e3.w;
  s0 += __shfl_xor(s0, 1);
  s0 += __shfl_xor(s0, 2);

  float sj[15];
#pragma unroll
  for (int j = 0; j < 15; ++j) {
    const float* kr = &Ks[i + j][q * 16];
    float4 k0 = *(const float4*)(kr);
    float4 k1 = *(const float4*)(kr + 4);
    float4 k2 = *(const float4*)(kr + 8);
    float4 k3 = *(const float4*)(kr + 12);
    float s = q0.x * k0.x + q0.y * k0.y + q0.z * k0.z + q0.w * k0.w +
              q1.x * k1.x + q1.y * k1.y + q1.z * k1.z + q1.w * k1.w +
              q2.x * k2.x + q2.y * k2.y + q2.z * k2.z + q2.w * k2.w +
              q3.x * k3.x + q3.y * k3.y + q3.z * k3.z + q3.w * k3.w;
    s += __shfl_xor(s, 1);
    s += __shfl_xor(s, 2);
    sj[j] = s;
  }

  if (q == 0) s0s[i] = s0;
  __syncthreads();
  if (tid < 64) {
    float v = s0s[tid];
    float m = v;
    for (int o = 1; o < 64; o <<= 1) m = fmaxf(m, __shfl_xor(m, o));
    float ee = expf(v - m);
    float s = ee;
    for (int o = 1; o < 64; o <<= 1) s += __shfl_xor(s, o);
    if (tid == 0) { red[0] = m; red[1] = s; }
  }
  __syncthreads();
  const float wt = expf(s0 - red[0]) / red[1];

  float mx = sj[0];
#pragma unroll
  for (int j = 1; j < 15; ++j) mx = fmaxf(mx, sj[j]);
  float pj[15], den = 0.f;
#pragma unroll
  for (int j = 0; j < 15; ++j) { pj[j] = expf(sj[j] - mx); den += pj[j]; }
  const float inv = 1.0f / den;

  float o[16] = {wt * e0.x, wt * e0.y, wt * e0.z, wt * e0.w,
                 wt * e1.x, wt * e1.y, wt * e1.z, wt * e1.w,
                 wt * e2.x, wt * e2.y, wt * e2.z, wt * e2.w,
                 wt * e3.x, wt * e3.y, wt * e3.z, wt * e3.w};
#pragma unroll
  for (int j = 0; j < 15; ++j) {
    float wj = pj[j] * inv;
    const float* vr = &Vs[i + j][q * 16];
#pragma unroll
    for (int dd = 0; dd < 16; ++dd) o[dd] = fmaf(wj, vr[dd], o[dd]);
  }
  _Float16 oh[16];
#pragma unroll
  for (int dd = 0; dd < 16; ++dd) oh[dd] = (_Float16)o[dd];
  *(float4*)(OFh + qbase) = *(float4*)&oh[0];
  *(float4*)(OFh + qbase + 8) = *(float4*)&oh[8];
}

// ---------------------------------------------------------------- K3: out proj
// M=16640, N=256, K=256. Block 64x64, 4 waves (each 32x32), BK=64 x 4 iters.
__global__ __launch_bounds__(256) void out_mfma(
    const float* __restrict__ x, const _Float16* __restrict__ ofh,
    const _Float16* __restrict__ wth, const float* __restrict__ bo,
    float* __restrict__ out) {
  __shared__ _Float16 Ah[64][72], Bh[64][72];
  const int tid = threadIdx.x;
  const int wave = tid >> 6, lane = tid & 63;
  const int ln = lane & 31, half = lane >> 5;
  const int mw = (wave & 1) * 32, nw = (wave >> 1) * 32;
  const int m0 = blockIdx.x * 64, n0 = blockIdx.y * 64;
  const int sr = tid >> 2, sc4 = (tid & 3) * 16;
  const int m = m0 + sr;
  const int b = m / 4160, tt = m % 4160;
  const bool useX = (tt < 64);
  const size_t xrow = ((size_t)(b * 4160 + tt)) * 256 + sc4;  // fp32 x
  const long obase = ((long)(b * 4) * 4096 + (tt - 64)) * 64 + sc4;
  const size_t bbase = (size_t)(n0 + sr) * 256 + sc4;

  float4 ra0, ra1, rb0, rb1;
  auto OLOAD = [&](int k0_) {
    if (useX) {
      float4 fx0 = *(const float4*)(x + xrow + k0_);
      float4 fx1 = *(const float4*)(x + xrow + k0_ + 4);
      float4 fx2 = *(const float4*)(x + xrow + k0_ + 8);
      float4 fx3 = *(const float4*)(x + xrow + k0_ + 12);
      _Float16 hh[16] = {
          (_Float16)fx0.x, (_Float16)fx0.y, (_Float16)fx0.z, (_Float16)fx0.w,
          (_Float16)fx1.x, (_Float16)fx1.y, (_Float16)fx1.z, (_Float16)fx1.w,
          (_Float16)fx2.x, (_Float16)fx2.y, (_Float16)fx2.z, (_Float16)fx2.w,
          (_Float16)fx3.x, (_Float16)fx3.y, (_Float16)fx3.z, (_Float16)fx3.w};
      ra0 = *(float4*)&hh[0];
      ra1 = *(float4*)&hh[8];
    } else {
      size_t o_ = (size_t)(obase + (long)(k0_ >> 6) * 262144);
      ra0 = *(const float4*)(ofh + o_);
      ra1 = *(const float4*)(ofh + o_ + 8);
    }
    rb0 = *(const float4*)(wth + bbase + k0_);
    rb1 = *(const float4*)(wth + bbase + k0_ + 8);
  };

  OLOAD(0);
  f32x16 acc = {};
  for (int it = 0; it < 4; ++it) {
    __syncthreads();
    *(float4*)&Ah[sr][sc4] = ra0;
    *(float4*)&Ah[sr][sc4 + 8] = ra1;
    *(float4*)&Bh[sr][sc4] = rb0;
    *(float4*)&Bh[sr][sc4 + 8] = rb1;
    __syncthreads();
    if (it < 3) OLOAD((it + 1) * 64);
#pragma unroll
    for (int ks = 0; ks < 4; ++ks) {
      const int kc = ks * 16 + half * 8;
      h8 ah = *(const h8*)&Ah[mw + ln][kc];
      h8 bh = *(const h8*)&Bh[nw + ln][kc];
      acc = __builtin_amdgcn_mfma_f32_32x32x16_f16(ah, bh, acc, 0, 0, 0);
    }
  }
  const int c = n0 + nw + ln;
  const float bias = bo[c];
  const int rb = m0 + mw + 4 * half;
#pragma unroll
  for (int reg = 0; reg < 16; ++reg) {
    int rr = rb + (reg & 3) + 8 * (reg >> 2);
    out[(size_t)rr * 256 + c] = acc[reg] + bias;
  }
}

// ---------------------------------------------------------------- launch
extern "C" void kernel_launch(void* const* d_in, const int* in_sizes, int n_in,
                              void* d_out, int out_size, void* d_ws, size_t ws_size,
                              hipStream_t stream) {
  const float* x  = (const float*)d_in[0];
  const float* wm = (const float*)d_in[1];
  const float* Wq = (const float*)d_in[2];
  const float* bq = (const float*)d_in[3];
  const float* Wo = (const float*)d_in[4];
  const float* bo = (const float*)d_in[5];
  float* out = (float*)d_out;
  float* ws = (float*)d_ws;

  float* Qb = ws;
  float* Kb = Qb + QN;
  float* Vb = Kb + QN;
  _Float16* OFh  = (_Float16*)(Vb + QN);
  _Float16* Wqth = OFh + QN;        // [768][256]
  _Float16* Woth = Wqth + 196608;   // [256][256]
  _Float16* wmTh = Woth + 65536;    // [4][4096][64]
  _Float16* xTh  = wmTh + 1048576;  // [4][256][64]
  // total ~59 MB of workspace

  conv_small<<<dim3(1284), 256, 0, stream>>>(x, wm, Wq, Wo, Wqth, Woth, wmTh,
                                             xTh);
  qkv_mfma<<<dim3(128, 6), 256, 0, stream>>>(x, Wqth, bq, Qb, Kb, Vb);
  attn_fused<<<dim3(64, 16), 256, 0, stream>>>(Qb, Kb, Vb, wmTh, xTh, OFh);
  out_mfma<<<dim3(260, 4), 256, 0, stream>>>(x, OFh, Woth, bo, out);
}